// Round 2
// baseline (1775.600 us; speedup 1.0000x reference)
//
#include <hip/hip_runtime.h>
#include <math.h>

typedef __bf16 bf16;
typedef __bf16 bf16x8 __attribute__((ext_vector_type(8)));
typedef float  f32x4  __attribute__((ext_vector_type(4)));

#define MFMA16(a,b,c) __builtin_amdgcn_mfma_f32_16x16x32_bf16((a),(b),(c),0,0,0)

#define B_SZ 4096
#define T_SZ 200
#define D_SZ 128
#define U_SZ 128
#define CHUNK 4
#define ROWS 8      // batch rows per augru block
#define ATTB 4      // batch elems per attn block

__device__ __forceinline__ float frcp_(float x) { return __builtin_amdgcn_rcpf(x); }
__device__ __forceinline__ float fsig(float x)  { return frcp_(1.0f + __expf(-x)); }
__device__ __forceinline__ float ftanh_(float x){ return 1.0f - 2.0f * frcp_(1.0f + __expf(2.0f * x)); }
// dice with moving_mean=0, moving_var=1: x_norm == x (1/sqrt(1+1e-9) rounds to 1.0f)
__device__ __forceinline__ float dicef(float x, float alpha) {
    float p = fsig(x);
    return alpha * (1.0f - p) * x + p * x;
}

// ---------------------------------------------------------------------------
// Prep: blocks 0..255 compute bias1[b,n] = q[b]@(W1a+W1c) via MFMA (16 rows each).
// Block 256 converts combined W1' -> bf16 [n][k] (k<128: W1b-W1c; k>=128: W1d)
// and W2^T -> bf16 [n][k].
// ---------------------------------------------------------------------------
__global__ __launch_bounds__(256) void prep_kernel(
    const float* __restrict__ Q,    // [B,128]
    const float* __restrict__ W1,   // [512,64]
    const float* __restrict__ W2,   // [64,16]
    float* __restrict__ BIAS,       // [B,64]
    bf16*  __restrict__ W1P,        // [64][256]
    bf16*  __restrict__ W2T)        // [16][64]
{
    const int tid = threadIdx.x;
    if (blockIdx.x == 256) {
        #pragma unroll 4
        for (int it = 0; it < 64; ++it) {
            int idx = it * 256 + tid;
            int k = idx >> 6;           // 0..255
            int n = idx & 63;
            float v;
            if (k < 128) v = W1[(128 + k) * 64 + n] - W1[(256 + k) * 64 + n];
            else         v = W1[(384 + (k - 128)) * 64 + n];
            W1P[n * 256 + k] = (bf16)v;
        }
        #pragma unroll
        for (int it = 0; it < 4; ++it) {
            int idx = it * 256 + tid; int k = idx >> 4; int n = idx & 15;
            W2T[n * 64 + k] = (bf16)W2[k * 16 + n];
        }
        return;
    }
    const int b0   = blockIdx.x * 16;
    const int lane = tid & 63;
    const int w    = tid >> 6;
    const int quad = lane >> 4;
    const int l15  = lane & 15;

    bf16x8 a[4];
    #pragma unroll
    for (int kk = 0; kk < 4; ++kk) {
        const float* p = Q + (long)(b0 + l15) * D_SZ + kk * 32 + quad * 8;
        float4 x0 = ((const float4*)p)[0];
        float4 x1 = ((const float4*)p)[1];
        float xv[8] = {x0.x, x0.y, x0.z, x0.w, x1.x, x1.y, x1.z, x1.w};
        #pragma unroll
        for (int j = 0; j < 8; ++j) a[kk][j] = (bf16)xv[j];
    }
    const int n = w * 16 + l15;
    f32x4 acc = {};
    #pragma unroll
    for (int kk = 0; kk < 4; ++kk) {
        bf16x8 bf;
        #pragma unroll
        for (int j = 0; j < 8; ++j) {
            int k = kk * 32 + quad * 8 + j;
            bf[j] = (bf16)(W1[k * 64 + n] + W1[(256 + k) * 64 + n]);
        }
        acc = MFMA16(a[kk], bf, acc);
    }
    #pragma unroll
    for (int i = 0; i < 4; ++i)
        BIAS[(long)(b0 + quad * 4 + i) * 64 + n] = acc[i];
}

// ---------------------------------------------------------------------------
// Kernel 1: attention scores. One block per ATTB batch elements, all T.
// h1 = dice(bias1 + x@W1' + (q*x)@W1''), h2 = dice(h1@W2), s = h2@W3,
// att[b,t] = t<len ? sigmoid(s) : 0
// B-fragments loaded straight from prepped global bf16 weights (L2-hot).
// ---------------------------------------------------------------------------
__global__ __launch_bounds__(256, 2) void attn_kernel(
    const float* __restrict__ X,    // [B,T,D]
    const float* __restrict__ Q,    // [B,D]
    const int*   __restrict__ LEN,  // [B,1]
    const float* __restrict__ A1,   // [64]
    const float* __restrict__ A2,   // [16]
    const float* __restrict__ W3,   // [16,1]
    const float* __restrict__ BIAS, // [B,64]
    const bf16*  __restrict__ W1P,  // [64][256]
    const bf16*  __restrict__ W2T,  // [16][64]
    float* __restrict__ ATT)        // [B,T]
{
    __shared__ bf16  H1s[64][72];   // per-wave 16-row dice(h1) buffer
    __shared__ float qf[128];
    __shared__ float bias_s[64];
    __shared__ float al1[64];
    __shared__ float al2[16];
    __shared__ float w3s[16];

    const int tid  = threadIdx.x;
    const int lane = tid & 63;
    const int w    = tid >> 6;
    const int quad = lane >> 4;
    const int l15  = lane & 15;

    if (tid < 64) al1[tid] = A1[tid];
    if (tid < 16) { al2[tid] = A2[tid]; w3s[tid] = W3[tid]; }

    // register B-fragments, straight from global (bf16, 16B loads)
    bf16x8 b1[4][8];
    #pragma unroll
    for (int nt = 0; nt < 4; ++nt)
        #pragma unroll
        for (int kk = 0; kk < 8; ++kk)
            b1[nt][kk] = *(const bf16x8*)(W1P + (nt * 16 + l15) * 256 + kk * 32 + quad * 8);
    bf16x8 b2[2];
    #pragma unroll
    for (int kk = 0; kk < 2; ++kk)
        b2[kk] = *(const bf16x8*)(W2T + l15 * 64 + kk * 32 + quad * 8);

    for (int bi = 0; bi < ATTB; ++bi) {
        const int b = blockIdx.x * ATTB + bi;
        __syncthreads();   // protect qf/bias_s reuse across bi
        if (tid < 128) qf[tid] = Q[(long)b * D_SZ + tid];
        else if (tid < 192) bias_s[tid - 128] = BIAS[(long)b * 64 + (tid - 128)];
        __syncthreads();
        const int len = LEN[b];

        for (int mt = w; mt < 13; mt += 4) {
            const int m0 = mt * 16;
            const int row = m0 + l15;
            const int rclamp = row < T_SZ ? row : (T_SZ - 1);
            const float* xp = X + ((long)b * T_SZ + rclamp) * D_SZ;

            f32x4 acc[4] = {};
            #pragma unroll
            for (int kc = 0; kc < 4; ++kc) {
                const float* p = xp + kc * 32 + quad * 8;
                float4 xa = ((const float4*)p)[0];
                float4 xb = ((const float4*)p)[1];
                float xv[8] = {xa.x, xa.y, xa.z, xa.w, xb.x, xb.y, xb.z, xb.w};
                const float4* qp = (const float4*)&qf[kc * 32 + quad * 8];
                float4 qa = qp[0], qb4 = qp[1];
                float qv[8] = {qa.x, qa.y, qa.z, qa.w, qb4.x, qb4.y, qb4.z, qb4.w};
                bf16x8 a_x, a_qx;
                #pragma unroll
                for (int j = 0; j < 8; ++j) {
                    a_x[j]  = (bf16)xv[j];
                    a_qx[j] = (bf16)(xv[j] * qv[j]);
                }
                #pragma unroll
                for (int nt = 0; nt < 4; ++nt) {
                    acc[nt] = MFMA16(a_x,  b1[nt][kc],     acc[nt]);
                    acc[nt] = MFMA16(a_qx, b1[nt][kc + 4], acc[nt]);
                }
            }
            // dice -> H1s (bf16, wave-local rows)
            #pragma unroll
            for (int nt = 0; nt < 4; ++nt) {
                int n = nt * 16 + l15;
                float bia = bias_s[n]; float al = al1[n];
                #pragma unroll
                for (int i = 0; i < 4; ++i) {
                    float v = acc[nt][i] + bia;
                    H1s[w * 16 + quad * 4 + i][n] = (bf16)dicef(v, al);
                }
            }
            // GEMM2: (16x64)@(64x16)
            f32x4 acc2 = {};
            #pragma unroll
            for (int kk = 0; kk < 2; ++kk) {
                bf16x8 a2 = *(const bf16x8*)&H1s[w * 16 + l15][kk * 32 + quad * 8];
                acc2 = MFMA16(a2, b2[kk], acc2);
            }
            // dice, dot W3, reduce 16 cols, write att
            {
                float al = al2[l15]; float w3 = w3s[l15];
                float s[4];
                #pragma unroll
                for (int i = 0; i < 4; ++i) s[i] = dicef(acc2[i], al) * w3;
                #pragma unroll
                for (int i = 0; i < 4; ++i) {
                    s[i] += __shfl_xor(s[i], 1, 64);
                    s[i] += __shfl_xor(s[i], 2, 64);
                    s[i] += __shfl_xor(s[i], 4, 64);
                    s[i] += __shfl_xor(s[i], 8, 64);
                }
                if (l15 == 0) {
                    #pragma unroll
                    for (int i = 0; i < 4; ++i) {
                        int t = m0 + quad * 4 + i;
                        if (t < T_SZ)
                            ATT[(long)b * T_SZ + t] = (t < len) ? fsig(s[i]) : 0.0f;
                    }
                }
            }
        }
    }
}

// ---------------------------------------------------------------------------
// Kernel 2: AUGRU recurrence. ROWS=8 batch rows/block, grid 512 -> 2 blocks/CU
// (independent barrier domains, 2 waves/SIMD). Weights in registers.
// Rows 8..15 of the M=16 MFMA tiles are zero-padded (stay exactly 0).
// Step order: r-gate -> RHb -> barrier -> u/c gates -> update.
// ---------------------------------------------------------------------------
__global__ __launch_bounds__(256, 2) void augru_kernel(
    const float* __restrict__ X,    // [B,T,D]
    const float* __restrict__ ATT,  // [B,T]
    const float* __restrict__ WU,   // [256,128]
    const float* __restrict__ WR,
    const float* __restrict__ WC,
    float* __restrict__ OUT)        // [B,128]
{
    __shared__ bf16  Xs[2][CHUNK][16][136];
    __shared__ float As[2][CHUNK][16];
    __shared__ bf16  Hb[16][136];
    __shared__ bf16  RHb[16][136];
    __shared__ float Hf[16][132];

    const int tid  = threadIdx.x;
    const int lane = tid & 63;
    const int w    = tid >> 6;
    const int quad = lane >> 4;
    const int l15  = lane & 15;
    const int b0   = blockIdx.x * ROWS;

    // zero-init everything (rows >= ROWS stay zero forever)
    for (int i = tid; i < 2 * CHUNK * 16 * 136; i += 256) ((bf16*)Xs)[i] = (bf16)0.f;
    for (int i = tid; i < 2 * CHUNK * 16; i += 256) ((float*)As)[i] = 0.f;
    for (int i = tid; i < 16 * 136; i += 256) { ((bf16*)Hb)[i] = (bf16)0.f; ((bf16*)RHb)[i] = (bf16)0.f; }
    for (int i = tid; i < 16 * 132; i += 256) ((float*)Hf)[i] = 0.f;

    // weight fragments: Wf[gate][part(0=x,1=h)][nt][kk], wave w owns cols w*32..
    bf16x8 Wf[3][2][2][4];
    {
        const float* Wg[3] = {WU, WR, WC};
        #pragma unroll
        for (int g = 0; g < 3; ++g)
            #pragma unroll
            for (int p = 0; p < 2; ++p)
                #pragma unroll
                for (int nt = 0; nt < 2; ++nt)
                    #pragma unroll
                    for (int kk = 0; kk < 4; ++kk) {
                        int n = w * 32 + nt * 16 + l15;
                        #pragma unroll
                        for (int i = 0; i < 8; ++i) {
                            int k = p * 128 + kk * 32 + quad * 8 + i;
                            Wf[g][p][nt][kk][i] = (bf16)Wg[g][k * 128 + n];
                        }
                    }
    }

    float4 pf[CHUNK];       // 8 rows * 4 steps * 128 f = 1024 float4 / 256 thr
    float  pa = 0.f;
    auto issue_loads = [&](int c) {
        #pragma unroll
        for (int it = 0; it < CHUNK; ++it) {
            int gidx = it * 256 + tid;
            int c4 = gidx & 31;
            int pair = gidx >> 5;
            int r = pair & 7;
            int s = pair >> 3;
            pf[it] = *(const float4*)(X + ((long)(b0 + r) * T_SZ + (c * CHUNK + s)) * D_SZ + c4 * 4);
        }
        if (tid < CHUNK * ROWS) {
            int r = tid & 7; int s = tid >> 3;
            pa = ATT[(long)(b0 + r) * T_SZ + c * CHUNK + s];
        }
    };
    auto commit = [&](int buf) {
        #pragma unroll
        for (int it = 0; it < CHUNK; ++it) {
            int gidx = it * 256 + tid;
            int c4 = gidx & 31;
            int pair = gidx >> 5;
            int r = pair & 7;
            int s = pair >> 3;
            bf16* dst = &Xs[buf][s][r][c4 * 4];
            float4 v = pf[it];
            dst[0] = (bf16)v.x; dst[1] = (bf16)v.y; dst[2] = (bf16)v.z; dst[3] = (bf16)v.w;
        }
        if (tid < CHUNK * ROWS) { int r = tid & 7; int s = tid >> 3; As[buf][s][r] = pa; }
    };

    issue_loads(0);
    __syncthreads();   // zero-init visible before commit overlaps
    commit(0);
    __syncthreads();

    const int NCH = T_SZ / CHUNK;   // 50
    for (int c = 0; c < NCH; ++c) {
        const int buf = c & 1;
        if (c + 1 < NCH) issue_loads(c + 1);

        #pragma unroll
        for (int s = 0; s < CHUNK; ++s) {
            // ---- phase A: r gate ----
            bf16x8 ax[4], ah[4];
            #pragma unroll
            for (int kk = 0; kk < 4; ++kk) {
                ax[kk] = *(const bf16x8*)&Xs[buf][s][l15][kk * 32 + quad * 8];
                ah[kk] = *(const bf16x8*)&Hb[l15][kk * 32 + quad * 8];
            }
            f32x4 pr[2] = {};
            #pragma unroll
            for (int nt = 0; nt < 2; ++nt)
                #pragma unroll
                for (int kk = 0; kk < 4; ++kk) {
                    pr[nt] = MFMA16(ax[kk], Wf[1][0][nt][kk], pr[nt]);
                    pr[nt] = MFMA16(ah[kk], Wf[1][1][nt][kk], pr[nt]);
                }
            float hc[2][4];
            #pragma unroll
            for (int nt = 0; nt < 2; ++nt) {
                int n = w * 32 + nt * 16 + l15;
                #pragma unroll
                for (int i = 0; i < 4; ++i) {
                    int row = quad * 4 + i;
                    float h = Hf[row][n];
                    hc[nt][i] = h;
                    float rr = fsig(pr[nt][i]);
                    RHb[row][n] = (bf16)(rr * h);
                }
            }
            __syncthreads();
            // ---- phase B: u and c gates ----
            bf16x8 ar[4];
            #pragma unroll
            for (int kk = 0; kk < 4; ++kk)
                ar[kk] = *(const bf16x8*)&RHb[l15][kk * 32 + quad * 8];
            f32x4 pu[2] = {}, pc[2] = {};
            #pragma unroll
            for (int nt = 0; nt < 2; ++nt)
                #pragma unroll
                for (int kk = 0; kk < 4; ++kk) {
                    pu[nt] = MFMA16(ax[kk], Wf[0][0][nt][kk], pu[nt]);
                    pu[nt] = MFMA16(ah[kk], Wf[0][1][nt][kk], pu[nt]);
                    pc[nt] = MFMA16(ax[kk], Wf[2][0][nt][kk], pc[nt]);
                    pc[nt] = MFMA16(ar[kk], Wf[2][1][nt][kk], pc[nt]);
                }
            #pragma unroll
            for (int nt = 0; nt < 2; ++nt) {
                int n = w * 32 + nt * 16 + l15;
                #pragma unroll
                for (int i = 0; i < 4; ++i) {
                    int row = quad * 4 + i;
                    float a  = As[buf][s][row];
                    float u  = fsig(pu[nt][i]);
                    float cg = ftanh_(pc[nt][i]);
                    float ut = u * a;
                    float hn = (1.f - ut) * hc[nt][i] + ut * cg;
                    Hf[row][n] = hn;
                    Hb[row][n] = (bf16)hn;
                }
            }
            __syncthreads();
        }
        if (c + 1 < NCH) commit(buf ^ 1);
        __syncthreads();
    }

    if (tid < 16 * ROWS) {
        int r = tid >> 4; int c8 = (tid & 15) * 8;
        #pragma unroll
        for (int j = 0; j < 8; ++j)
            OUT[(long)(b0 + r) * U_SZ + c8 + j] = Hf[r][c8 + j];
    }
}

extern "C" void kernel_launch(void* const* d_in, const int* in_sizes, int n_in,
                              void* d_out, int out_size, void* d_ws, size_t ws_size,
                              hipStream_t stream) {
    const float* X   = (const float*)d_in[0];
    const float* Q   = (const float*)d_in[1];
    const int*   LEN = (const int*)d_in[2];
    const float* W1  = (const float*)d_in[3];
    const float* A1  = (const float*)d_in[4];
    const float* W2  = (const float*)d_in[5];
    const float* A2  = (const float*)d_in[6];
    const float* W3  = (const float*)d_in[7];
    const float* WU  = (const float*)d_in[8];
    const float* WR  = (const float*)d_in[9];
    const float* WC  = (const float*)d_in[10];
    float* OUT = (float*)d_out;

    // workspace layout
    float* ATT  = (float*)d_ws;                       // B*T fp32   (3.28 MB)
    float* BIAS = ATT + (size_t)B_SZ * T_SZ;          // B*64 fp32  (1.05 MB)
    bf16*  W1P  = (bf16*)(BIAS + (size_t)B_SZ * 64);  // 64*256 bf16
    bf16*  W2T  = W1P + 64 * 256;                     // 16*64 bf16

    prep_kernel<<<257, 256, 0, stream>>>(Q, W1, W2, BIAS, W1P, W2T);
    attn_kernel<<<B_SZ / ATTB, 256, 0, stream>>>(X, Q, LEN, A1, A2, W3, BIAS, W1P, W2T, ATT);
    augru_kernel<<<B_SZ / ROWS, 256, 0, stream>>>(X, ATT, WU, WR, WC, OUT);
}

// Round 3
// 1097.639 us; speedup vs baseline: 1.6177x; 1.6177x over previous
//
#include <hip/hip_runtime.h>
#include <math.h>

typedef __bf16 bf16;
typedef __bf16 bf16x8 __attribute__((ext_vector_type(8)));
typedef float  f32x4  __attribute__((ext_vector_type(4)));

#define MFMA16(a,b,c) __builtin_amdgcn_mfma_f32_16x16x32_bf16((a),(b),(c),0,0,0)

#define B_SZ 4096
#define T_SZ 200
#define D_SZ 128
#define U_SZ 128
#define CHUNK 4
#define ROWS 8      // batch rows per augru block -> grid 512 -> 2 blocks/CU
#define ATTB 4      // batch elems per attn block

__device__ __forceinline__ float frcp_(float x) { return __builtin_amdgcn_rcpf(x); }
__device__ __forceinline__ float fsig(float x)  { return frcp_(1.0f + __expf(-x)); }
__device__ __forceinline__ float ftanh_(float x){ return 1.0f - 2.0f * frcp_(1.0f + __expf(2.0f * x)); }
// dice with moving_mean=0, moving_var=1: x_norm == x (1/sqrt(1+1e-9) rounds to 1.0f)
__device__ __forceinline__ float dicef(float x, float alpha) {
    float p = fsig(x);
    return alpha * (1.0f - p) * x + p * x;
}

// ---------------------------------------------------------------------------
// Prep: blocks 0..255 compute bias1[b,n] = q[b]@(W1a+W1c) via MFMA (16 rows each).
// Block 256 converts combined W1' -> bf16 [n][k] (k<128: W1b-W1c; k>=128: W1d)
// and W2^T -> bf16 [n][k].
// ---------------------------------------------------------------------------
__global__ __launch_bounds__(256) void prep_kernel(
    const float* __restrict__ Q,    // [B,128]
    const float* __restrict__ W1,   // [512,64]
    const float* __restrict__ W2,   // [64,16]
    float* __restrict__ BIAS,       // [B,64]
    bf16*  __restrict__ W1P,        // [64][256]
    bf16*  __restrict__ W2T)        // [16][64]
{
    const int tid = threadIdx.x;
    if (blockIdx.x == 256) {
        #pragma unroll 4
        for (int it = 0; it < 64; ++it) {
            int idx = it * 256 + tid;
            int k = idx >> 6;           // 0..255
            int n = idx & 63;
            float v;
            if (k < 128) v = W1[(128 + k) * 64 + n] - W1[(256 + k) * 64 + n];
            else         v = W1[(384 + (k - 128)) * 64 + n];
            W1P[n * 256 + k] = (bf16)v;
        }
        #pragma unroll
        for (int it = 0; it < 4; ++it) {
            int idx = it * 256 + tid; int k = idx >> 4; int n = idx & 15;
            W2T[n * 64 + k] = (bf16)W2[k * 16 + n];
        }
        return;
    }
    const int b0   = blockIdx.x * 16;
    const int lane = tid & 63;
    const int w    = tid >> 6;
    const int quad = lane >> 4;
    const int l15  = lane & 15;

    bf16x8 a[4];
    #pragma unroll
    for (int kk = 0; kk < 4; ++kk) {
        const float* p = Q + (long)(b0 + l15) * D_SZ + kk * 32 + quad * 8;
        float4 x0 = ((const float4*)p)[0];
        float4 x1 = ((const float4*)p)[1];
        float xv[8] = {x0.x, x0.y, x0.z, x0.w, x1.x, x1.y, x1.z, x1.w};
        #pragma unroll
        for (int j = 0; j < 8; ++j) a[kk][j] = (bf16)xv[j];
    }
    const int n = w * 16 + l15;
    f32x4 acc = {};
    #pragma unroll
    for (int kk = 0; kk < 4; ++kk) {
        bf16x8 bf;
        #pragma unroll
        for (int j = 0; j < 8; ++j) {
            int k = kk * 32 + quad * 8 + j;
            bf[j] = (bf16)(W1[k * 64 + n] + W1[(256 + k) * 64 + n]);
        }
        acc = MFMA16(a[kk], bf, acc);
    }
    #pragma unroll
    for (int i = 0; i < 4; ++i)
        BIAS[(long)(b0 + quad * 4 + i) * 64 + n] = acc[i];
}

// ---------------------------------------------------------------------------
// Kernel 1: attention scores. One block per ATTB batch elements, all T.
// h1 = dice(bias1 + x@W1' + (q*x)@W1''), h2 = dice(h1@W2), s = h2@W3,
// att[b,t] = t<len ? sigmoid(s) : 0
// NOTE: plain __launch_bounds__(256) — a min-waves=2 cap (128 VGPR) spills
// the 136 VGPRs of register-resident B-fragments (round-2 regression).
// ---------------------------------------------------------------------------
__global__ __launch_bounds__(256) void attn_kernel(
    const float* __restrict__ X,    // [B,T,D]
    const float* __restrict__ Q,    // [B,D]
    const int*   __restrict__ LEN,  // [B,1]
    const float* __restrict__ A1,   // [64]
    const float* __restrict__ A2,   // [16]
    const float* __restrict__ W3,   // [16,1]
    const float* __restrict__ BIAS, // [B,64]
    const bf16*  __restrict__ W1P,  // [64][256]
    const bf16*  __restrict__ W2T,  // [16][64]
    float* __restrict__ ATT)        // [B,T]
{
    __shared__ bf16  H1s[64][72];   // per-wave 16-row dice(h1) buffer
    __shared__ float qf[128];
    __shared__ float bias_s[64];
    __shared__ float al1[64];
    __shared__ float al2[16];
    __shared__ float w3s[16];

    const int tid  = threadIdx.x;
    const int lane = tid & 63;
    const int w    = tid >> 6;
    const int quad = lane >> 4;
    const int l15  = lane & 15;

    if (tid < 64) al1[tid] = A1[tid];
    if (tid < 16) { al2[tid] = A2[tid]; w3s[tid] = W3[tid]; }

    // register B-fragments, straight from global (bf16, 16B loads, L2-hot)
    bf16x8 b1[4][8];
    #pragma unroll
    for (int nt = 0; nt < 4; ++nt)
        #pragma unroll
        for (int kk = 0; kk < 8; ++kk)
            b1[nt][kk] = *(const bf16x8*)(W1P + (nt * 16 + l15) * 256 + kk * 32 + quad * 8);
    bf16x8 b2[2];
    #pragma unroll
    for (int kk = 0; kk < 2; ++kk)
        b2[kk] = *(const bf16x8*)(W2T + l15 * 64 + kk * 32 + quad * 8);

    for (int bi = 0; bi < ATTB; ++bi) {
        const int b = blockIdx.x * ATTB + bi;
        __syncthreads();   // protect qf/bias_s reuse across bi
        if (tid < 128) qf[tid] = Q[(long)b * D_SZ + tid];
        else if (tid < 192) bias_s[tid - 128] = BIAS[(long)b * 64 + (tid - 128)];
        __syncthreads();
        const int len = LEN[b];

        for (int mt = w; mt < 13; mt += 4) {
            const int m0 = mt * 16;
            const int row = m0 + l15;
            const int rclamp = row < T_SZ ? row : (T_SZ - 1);
            const float* xp = X + ((long)b * T_SZ + rclamp) * D_SZ;

            f32x4 acc[4] = {};
            #pragma unroll
            for (int kc = 0; kc < 4; ++kc) {
                const float* p = xp + kc * 32 + quad * 8;
                float4 xa = ((const float4*)p)[0];
                float4 xb = ((const float4*)p)[1];
                float xv[8] = {xa.x, xa.y, xa.z, xa.w, xb.x, xb.y, xb.z, xb.w};
                const float4* qp = (const float4*)&qf[kc * 32 + quad * 8];
                float4 qa = qp[0], qb4 = qp[1];
                float qv[8] = {qa.x, qa.y, qa.z, qa.w, qb4.x, qb4.y, qb4.z, qb4.w};
                bf16x8 a_x, a_qx;
                #pragma unroll
                for (int j = 0; j < 8; ++j) {
                    a_x[j]  = (bf16)xv[j];
                    a_qx[j] = (bf16)(xv[j] * qv[j]);
                }
                #pragma unroll
                for (int nt = 0; nt < 4; ++nt) {
                    acc[nt] = MFMA16(a_x,  b1[nt][kc],     acc[nt]);
                    acc[nt] = MFMA16(a_qx, b1[nt][kc + 4], acc[nt]);
                }
            }
            // dice -> H1s (bf16, wave-local rows)
            #pragma unroll
            for (int nt = 0; nt < 4; ++nt) {
                int n = nt * 16 + l15;
                float bia = bias_s[n]; float al = al1[n];
                #pragma unroll
                for (int i = 0; i < 4; ++i) {
                    float v = acc[nt][i] + bia;
                    H1s[w * 16 + quad * 4 + i][n] = (bf16)dicef(v, al);
                }
            }
            // GEMM2: (16x64)@(64x16)
            f32x4 acc2 = {};
            #pragma unroll
            for (int kk = 0; kk < 2; ++kk) {
                bf16x8 a2 = *(const bf16x8*)&H1s[w * 16 + l15][kk * 32 + quad * 8];
                acc2 = MFMA16(a2, b2[kk], acc2);
            }
            // dice, dot W3, reduce 16 cols, write att
            {
                float al = al2[l15]; float w3 = w3s[l15];
                float s[4];
                #pragma unroll
                for (int i = 0; i < 4; ++i) s[i] = dicef(acc2[i], al) * w3;
                #pragma unroll
                for (int i = 0; i < 4; ++i) {
                    s[i] += __shfl_xor(s[i], 1, 64);
                    s[i] += __shfl_xor(s[i], 2, 64);
                    s[i] += __shfl_xor(s[i], 4, 64);
                    s[i] += __shfl_xor(s[i], 8, 64);
                }
                if (l15 == 0) {
                    #pragma unroll
                    for (int i = 0; i < 4; ++i) {
                        int t = m0 + quad * 4 + i;
                        if (t < T_SZ)
                            ATT[(long)b * T_SZ + t] = (t < len) ? fsig(s[i]) : 0.0f;
                    }
                }
            }
        }
    }
}

// ---------------------------------------------------------------------------
// Kernel 2: AUGRU recurrence. ROWS=8 rows/block, grid 512 -> 2 blocks/CU
// (needs VGPR<=256: weight fragments are 192 VGPR, total ~224 -> fits 2
// waves/SIMD; do NOT add a min-waves launch bound or they spill).
// Rows 8..15 of the M=16 MFMA tiles are zero-padded (stay exactly 0).
// ---------------------------------------------------------------------------
__global__ __launch_bounds__(256, 1) void augru_kernel(
    const float* __restrict__ X,    // [B,T,D]
    const float* __restrict__ ATT,  // [B,T]
    const float* __restrict__ WU,   // [256,128]
    const float* __restrict__ WR,
    const float* __restrict__ WC,
    float* __restrict__ OUT)        // [B,128]
{
    __shared__ bf16  Xs[2][CHUNK][16][136];
    __shared__ float As[2][CHUNK][16];
    __shared__ bf16  Hb[16][136];
    __shared__ bf16  RHb[16][136];
    __shared__ float Hf[16][132];

    const int tid  = threadIdx.x;
    const int lane = tid & 63;
    const int w    = tid >> 6;
    const int quad = lane >> 4;
    const int l15  = lane & 15;
    const int b0   = blockIdx.x * ROWS;

    // zero-init everything (rows >= ROWS stay zero forever)
    for (int i = tid; i < 2 * CHUNK * 16 * 136; i += 256) ((bf16*)Xs)[i] = (bf16)0.f;
    for (int i = tid; i < 2 * CHUNK * 16; i += 256) ((float*)As)[i] = 0.f;
    for (int i = tid; i < 16 * 136; i += 256) { ((bf16*)Hb)[i] = (bf16)0.f; ((bf16*)RHb)[i] = (bf16)0.f; }
    for (int i = tid; i < 16 * 132; i += 256) ((float*)Hf)[i] = 0.f;

    // weight fragments: Wf[gate][part(0=x,1=h)][nt][kk], wave w owns cols w*32..
    bf16x8 Wf[3][2][2][4];
    {
        const float* Wg[3] = {WU, WR, WC};
        #pragma unroll
        for (int g = 0; g < 3; ++g)
            #pragma unroll
            for (int p = 0; p < 2; ++p)
                #pragma unroll
                for (int nt = 0; nt < 2; ++nt)
                    #pragma unroll
                    for (int kk = 0; kk < 4; ++kk) {
                        int n = w * 32 + nt * 16 + l15;
                        #pragma unroll
                        for (int i = 0; i < 8; ++i) {
                            int k = p * 128 + kk * 32 + quad * 8 + i;
                            Wf[g][p][nt][kk][i] = (bf16)Wg[g][k * 128 + n];
                        }
                    }
    }

    float4 pf[CHUNK];       // 8 rows * 4 steps * 128 f = 1024 float4 / 256 thr
    float  pa = 0.f;
    auto issue_loads = [&](int c) {
        #pragma unroll
        for (int it = 0; it < CHUNK; ++it) {
            int gidx = it * 256 + tid;
            int c4 = gidx & 31;
            int pair = gidx >> 5;
            int r = pair & 7;
            int s = pair >> 3;
            pf[it] = *(const float4*)(X + ((long)(b0 + r) * T_SZ + (c * CHUNK + s)) * D_SZ + c4 * 4);
        }
        if (tid < CHUNK * ROWS) {
            int r = tid & 7; int s = tid >> 3;
            pa = ATT[(long)(b0 + r) * T_SZ + c * CHUNK + s];
        }
    };
    auto commit = [&](int buf) {
        #pragma unroll
        for (int it = 0; it < CHUNK; ++it) {
            int gidx = it * 256 + tid;
            int c4 = gidx & 31;
            int pair = gidx >> 5;
            int r = pair & 7;
            int s = pair >> 3;
            bf16* dst = &Xs[buf][s][r][c4 * 4];
            float4 v = pf[it];
            dst[0] = (bf16)v.x; dst[1] = (bf16)v.y; dst[2] = (bf16)v.z; dst[3] = (bf16)v.w;
        }
        if (tid < CHUNK * ROWS) { int r = tid & 7; int s = tid >> 3; As[buf][s][r] = pa; }
    };

    issue_loads(0);
    __syncthreads();   // zero-init visible before commit
    commit(0);
    __syncthreads();

    const int NCH = T_SZ / CHUNK;   // 50
    for (int c = 0; c < NCH; ++c) {
        const int buf = c & 1;
        if (c + 1 < NCH) issue_loads(c + 1);

        #pragma unroll
        for (int s = 0; s < CHUNK; ++s) {
            // ---- phase A: r gate ----
            bf16x8 ax[4], ah[4];
            #pragma unroll
            for (int kk = 0; kk < 4; ++kk) {
                ax[kk] = *(const bf16x8*)&Xs[buf][s][l15][kk * 32 + quad * 8];
                ah[kk] = *(const bf16x8*)&Hb[l15][kk * 32 + quad * 8];
            }
            f32x4 pr[2] = {};
            #pragma unroll
            for (int nt = 0; nt < 2; ++nt)
                #pragma unroll
                for (int kk = 0; kk < 4; ++kk) {
                    pr[nt] = MFMA16(ax[kk], Wf[1][0][nt][kk], pr[nt]);
                    pr[nt] = MFMA16(ah[kk], Wf[1][1][nt][kk], pr[nt]);
                }
            float hc[2][4];
            #pragma unroll
            for (int nt = 0; nt < 2; ++nt) {
                int n = w * 32 + nt * 16 + l15;
                #pragma unroll
                for (int i = 0; i < 4; ++i) {
                    int row = quad * 4 + i;
                    float h = Hf[row][n];
                    hc[nt][i] = h;
                    float rr = fsig(pr[nt][i]);
                    RHb[row][n] = (bf16)(rr * h);
                }
            }
            __syncthreads();
            // ---- phase B: u and c gates ----
            bf16x8 ar[4];
            #pragma unroll
            for (int kk = 0; kk < 4; ++kk)
                ar[kk] = *(const bf16x8*)&RHb[l15][kk * 32 + quad * 8];
            f32x4 pu[2] = {}, pc[2] = {};
            #pragma unroll
            for (int nt = 0; nt < 2; ++nt)
                #pragma unroll
                for (int kk = 0; kk < 4; ++kk) {
                    pu[nt] = MFMA16(ax[kk], Wf[0][0][nt][kk], pu[nt]);
                    pu[nt] = MFMA16(ah[kk], Wf[0][1][nt][kk], pu[nt]);
                    pc[nt] = MFMA16(ax[kk], Wf[2][0][nt][kk], pc[nt]);
                    pc[nt] = MFMA16(ar[kk], Wf[2][1][nt][kk], pc[nt]);
                }
            #pragma unroll
            for (int nt = 0; nt < 2; ++nt) {
                int n = w * 32 + nt * 16 + l15;
                #pragma unroll
                for (int i = 0; i < 4; ++i) {
                    int row = quad * 4 + i;
                    float a  = As[buf][s][row];
                    float u  = fsig(pu[nt][i]);
                    float cg = ftanh_(pc[nt][i]);
                    float ut = u * a;
                    float hn = (1.f - ut) * hc[nt][i] + ut * cg;
                    Hf[row][n] = hn;
                    Hb[row][n] = (bf16)hn;
                }
            }
            __syncthreads();
        }
        if (c + 1 < NCH) commit(buf ^ 1);
        __syncthreads();
    }

    if (tid < 16 * ROWS) {
        int r = tid >> 4; int c8 = (tid & 15) * 8;
        #pragma unroll
        for (int j = 0; j < 8; ++j)
            OUT[(long)(b0 + r) * U_SZ + c8 + j] = Hf[r][c8 + j];
    }
}

extern "C" void kernel_launch(void* const* d_in, const int* in_sizes, int n_in,
                              void* d_out, int out_size, void* d_ws, size_t ws_size,
                              hipStream_t stream) {
    const float* X   = (const float*)d_in[0];
    const float* Q   = (const float*)d_in[1];
    const int*   LEN = (const int*)d_in[2];
    const float* W1  = (const float*)d_in[3];
    const float* A1  = (const float*)d_in[4];
    const float* W2  = (const float*)d_in[5];
    const float* A2  = (const float*)d_in[6];
    const float* W3  = (const float*)d_in[7];
    const float* WU  = (const float*)d_in[8];
    const float* WR  = (const float*)d_in[9];
    const float* WC  = (const float*)d_in[10];
    float* OUT = (float*)d_out;

    // workspace layout
    float* ATT  = (float*)d_ws;                       // B*T fp32   (3.28 MB)
    float* BIAS = ATT + (size_t)B_SZ * T_SZ;          // B*64 fp32  (1.05 MB)
    bf16*  W1P  = (bf16*)(BIAS + (size_t)B_SZ * 64);  // 64*256 bf16
    bf16*  W2T  = W1P + 64 * 256;                     // 16*64 bf16

    prep_kernel<<<257, 256, 0, stream>>>(Q, W1, W2, BIAS, W1P, W2T);
    attn_kernel<<<B_SZ / ATTB, 256, 0, stream>>>(X, Q, LEN, A1, A2, W3, BIAS, W1P, W2T, ATT);
    augru_kernel<<<B_SZ / ROWS, 256, 0, stream>>>(X, ATT, WU, WR, WC, OUT);
}

// Round 4
// 812.043 us; speedup vs baseline: 2.1866x; 1.3517x over previous
//
#include <hip/hip_runtime.h>
#include <math.h>

typedef __bf16 bf16;
typedef __bf16 bf16x8 __attribute__((ext_vector_type(8)));
typedef float  f32x4  __attribute__((ext_vector_type(4)));

#define MFMA16(a,b,c) __builtin_amdgcn_mfma_f32_16x16x32_bf16((a),(b),(c),0,0,0)

#define B_SZ 4096
#define T_SZ 200
#define D_SZ 128
#define U_SZ 128
#define ACHUNK 4
#define AROWS 16    // batch rows per augru block (full M=16 MFMA tiles)
#define ATTB 8      // batch elems per attn block

__device__ __forceinline__ float frcp_(float x) { return __builtin_amdgcn_rcpf(x); }
__device__ __forceinline__ float fsig(float x)  { return frcp_(1.0f + __expf(-x)); }
__device__ __forceinline__ float ftanh_(float x){ return 1.0f - 2.0f * frcp_(1.0f + __expf(2.0f * x)); }
// dice with moving_mean=0, moving_var=1: x_norm == x (1/sqrt(1+1e-9) rounds to 1.0f)
__device__ __forceinline__ float dicef(float x, float alpha) {
    float p = fsig(x);
    return alpha * (1.0f - p) * x + p * x;
}

// ---------------------------------------------------------------------------
// Prep: blocks 0..255 compute bias1[b,n] = q[b]@(W1a+W1c) via MFMA (16 rows each).
// Block 256 converts combined W1' -> bf16 [n][k] (k<128: W1b-W1c; k>=128: W1d)
// and W2^T -> bf16 [n][k].
// ---------------------------------------------------------------------------
__global__ __launch_bounds__(256) void prep_kernel(
    const float* __restrict__ Q,    // [B,128]
    const float* __restrict__ W1,   // [512,64]
    const float* __restrict__ W2,   // [64,16]
    float* __restrict__ BIAS,       // [B,64]
    bf16*  __restrict__ W1P,        // [64][256]
    bf16*  __restrict__ W2T)        // [16][64]
{
    const int tid = threadIdx.x;
    if (blockIdx.x == 256) {
        #pragma unroll 4
        for (int it = 0; it < 64; ++it) {
            int idx = it * 256 + tid;
            int k = idx >> 6;           // 0..255
            int n = idx & 63;
            float v;
            if (k < 128) v = W1[(128 + k) * 64 + n] - W1[(256 + k) * 64 + n];
            else         v = W1[(384 + (k - 128)) * 64 + n];
            W1P[n * 256 + k] = (bf16)v;
        }
        #pragma unroll
        for (int it = 0; it < 4; ++it) {
            int idx = it * 256 + tid; int k = idx >> 4; int n = idx & 15;
            W2T[n * 64 + k] = (bf16)W2[k * 16 + n];
        }
        return;
    }
    const int b0   = blockIdx.x * 16;
    const int lane = tid & 63;
    const int w    = tid >> 6;
    const int quad = lane >> 4;
    const int l15  = lane & 15;

    bf16x8 a[4];
    #pragma unroll
    for (int kk = 0; kk < 4; ++kk) {
        const float* p = Q + (long)(b0 + l15) * D_SZ + kk * 32 + quad * 8;
        float4 x0 = ((const float4*)p)[0];
        float4 x1 = ((const float4*)p)[1];
        float xv[8] = {x0.x, x0.y, x0.z, x0.w, x1.x, x1.y, x1.z, x1.w};
        #pragma unroll
        for (int j = 0; j < 8; ++j) a[kk][j] = (bf16)xv[j];
    }
    const int n = w * 16 + l15;
    f32x4 acc = {};
    #pragma unroll
    for (int kk = 0; kk < 4; ++kk) {
        bf16x8 bf;
        #pragma unroll
        for (int j = 0; j < 8; ++j) {
            int k = kk * 32 + quad * 8 + j;
            bf[j] = (bf16)(W1[k * 64 + n] + W1[(256 + k) * 64 + n]);
        }
        acc = MFMA16(a[kk], bf, acc);
    }
    #pragma unroll
    for (int i = 0; i < 4; ++i)
        BIAS[(long)(b0 + quad * 4 + i) * 64 + n] = acc[i];
}

// ---------------------------------------------------------------------------
// Kernel 1: attention scores. ATTB=8 batch elems per block, flattened
// (bi, mt) tile loop with software-pipelined X loads; ONE barrier total.
// ---------------------------------------------------------------------------
__global__ __launch_bounds__(256) void attn_kernel(
    const float* __restrict__ X,    // [B,T,D]
    const float* __restrict__ Q,    // [B,D]
    const int*   __restrict__ LEN,  // [B,1]
    const float* __restrict__ A1,   // [64]
    const float* __restrict__ A2,   // [16]
    const float* __restrict__ W3,   // [16,1]
    const float* __restrict__ BIAS, // [B,64]
    const bf16*  __restrict__ W1P,  // [64][256]
    const bf16*  __restrict__ W2T,  // [16][64]
    float* __restrict__ ATT)        // [B,T]
{
    __shared__ bf16  H1s[64][72];       // wave-private 16-row dice(h1) buffer
    __shared__ float qf[ATTB][128];
    __shared__ float bias_s[ATTB][64];
    __shared__ float al1[64];
    __shared__ float al2[16];
    __shared__ float w3s[16];
    __shared__ int   lens[ATTB];

    const int tid  = threadIdx.x;
    const int lane = tid & 63;
    const int w    = tid >> 6;
    const int quad = lane >> 4;
    const int l15  = lane & 15;
    const long b0  = (long)blockIdx.x * ATTB;

    for (int i = tid; i < ATTB * 128; i += 256) qf[i >> 7][i & 127] = Q[b0 * 128 + i];
    for (int i = tid; i < ATTB * 64;  i += 256) bias_s[i >> 6][i & 63] = BIAS[b0 * 64 + i];
    if (tid < 64) al1[tid] = A1[tid];
    if (tid < 16) { al2[tid] = A2[tid]; w3s[tid] = W3[tid]; }
    if (tid < ATTB) lens[tid] = LEN[b0 + tid];

    // register B-fragments straight from prepped global bf16 (L2-hot)
    bf16x8 b1[4][8];
    #pragma unroll
    for (int nt = 0; nt < 4; ++nt)
        #pragma unroll
        for (int kk = 0; kk < 8; ++kk)
            b1[nt][kk] = *(const bf16x8*)(W1P + (nt * 16 + l15) * 256 + kk * 32 + quad * 8);
    bf16x8 b2[2];
    #pragma unroll
    for (int kk = 0; kk < 2; ++kk)
        b2[kk] = *(const bf16x8*)(W2T + l15 * 64 + kk * 32 + quad * 8);
    __syncthreads();

    const int NT = 13 * ATTB;
    float4 fb[8];
    auto issue = [&](int g) {
        int bi = g / 13, mt = g - bi * 13;
        int row = mt * 16 + l15;
        int rc  = row < T_SZ ? row : (T_SZ - 1);
        const float* xp = X + ((b0 + bi) * T_SZ + rc) * D_SZ;
        #pragma unroll
        for (int kc = 0; kc < 4; ++kc) {
            const float* p = xp + kc * 32 + quad * 8;
            fb[kc * 2]     = ((const float4*)p)[0];
            fb[kc * 2 + 1] = ((const float4*)p)[1];
        }
    };
    auto convert = [&](int g, bf16x8* axd, bf16x8* aqd) {
        int bi = g / 13;
        #pragma unroll
        for (int kc = 0; kc < 4; ++kc) {
            float4 xa = fb[kc * 2], xb = fb[kc * 2 + 1];
            float xv[8] = {xa.x, xa.y, xa.z, xa.w, xb.x, xb.y, xb.z, xb.w};
            const float* qp = &qf[bi][kc * 32 + quad * 8];
            #pragma unroll
            for (int j = 0; j < 8; ++j) {
                axd[kc][j] = (bf16)xv[j];
                aqd[kc][j] = (bf16)(xv[j] * qp[j]);
            }
        }
    };

    bf16x8 axc[4], aqc[4];
    issue(w);
    convert(w, axc, aqc);

    for (int g = w; g < NT; g += 4) {
        const int gn = g + 4;
        if (gn < NT) issue(gn);            // loads in flight over MFMAs below

        f32x4 acc[4] = {};
        #pragma unroll
        for (int kc = 0; kc < 4; ++kc)
            #pragma unroll
            for (int nt = 0; nt < 4; ++nt) {
                acc[nt] = MFMA16(axc[kc], b1[nt][kc],     acc[nt]);
                acc[nt] = MFMA16(aqc[kc], b1[nt][kc + 4], acc[nt]);
            }

        const int bi = g / 13, mt = g - bi * 13;
        const int m0 = mt * 16;
        #pragma unroll
        for (int nt = 0; nt < 4; ++nt) {
            int n = nt * 16 + l15;
            float bia = bias_s[bi][n]; float al = al1[n];
            #pragma unroll
            for (int i = 0; i < 4; ++i) {
                float v = acc[nt][i] + bia;
                H1s[w * 16 + quad * 4 + i][n] = (bf16)dicef(v, al);
            }
        }
        f32x4 acc2 = {};
        #pragma unroll
        for (int kk = 0; kk < 2; ++kk) {
            bf16x8 a2 = *(const bf16x8*)&H1s[w * 16 + l15][kk * 32 + quad * 8];
            acc2 = MFMA16(a2, b2[kk], acc2);
        }
        {
            float al = al2[l15]; float w3 = w3s[l15];
            float s[4];
            #pragma unroll
            for (int i = 0; i < 4; ++i) s[i] = dicef(acc2[i], al) * w3;
            #pragma unroll
            for (int i = 0; i < 4; ++i) {
                s[i] += __shfl_xor(s[i], 1, 64);
                s[i] += __shfl_xor(s[i], 2, 64);
                s[i] += __shfl_xor(s[i], 4, 64);
                s[i] += __shfl_xor(s[i], 8, 64);
            }
            if (l15 == 0) {
                int len = lens[bi];
                #pragma unroll
                for (int i = 0; i < 4; ++i) {
                    int t = m0 + quad * 4 + i;
                    if (t < T_SZ)
                        ATT[(b0 + bi) * T_SZ + t] = (t < len) ? fsig(s[i]) : 0.0f;
                }
            }
        }
        if (gn < NT) convert(gn, axc, aqc);
    }
}

// ---------------------------------------------------------------------------
// Kernel 2: AUGRU. 512 threads (8 waves), 16 rows/block (full M=16 tiles),
// wave w owns output cols [w*16, w*16+16) -> weights only 96 VGPR/wave.
// h is LANE-PRIVATE fp32 registers (lane (quad,l15) of wave w owns
// h[rows quad*4..+3][col w*16+l15]); Hb/RHb bf16 LDS only for MFMA operands.
// u/c x-part MFMAs issued between RHb write and barrier (hide barrier wait).
// ---------------------------------------------------------------------------
__global__ __launch_bounds__(512) void augru_kernel(
    const float* __restrict__ X,    // [B,T,D]
    const float* __restrict__ ATT,  // [B,T]
    const float* __restrict__ WU,   // [256,128]
    const float* __restrict__ WR,
    const float* __restrict__ WC,
    float* __restrict__ OUT)        // [B,128]
{
    __shared__ bf16  Xs[2][ACHUNK][16][136];
    __shared__ float As[2][ACHUNK][16];
    __shared__ bf16  Hb[16][136];
    __shared__ bf16  RHb[16][136];

    const int tid  = threadIdx.x;
    const int lane = tid & 63;
    const int w    = tid >> 6;      // 0..7
    const int quad = lane >> 4;
    const int l15  = lane & 15;
    const int b0   = blockIdx.x * AROWS;
    const int n    = w * 16 + l15;  // this lane's output column

    for (int i = tid; i < 16 * 136; i += 512) { ((bf16*)Hb)[i] = (bf16)0.f; ((bf16*)RHb)[i] = (bf16)0.f; }

    // per-wave weight slice: Wf[gate][part(0=x,1=h)][kk], 24 frags = 96 VGPR
    bf16x8 Wf[3][2][4];
    {
        const float* Wg[3] = {WU, WR, WC};
        #pragma unroll
        for (int g = 0; g < 3; ++g)
            #pragma unroll
            for (int p = 0; p < 2; ++p)
                #pragma unroll
                for (int kk = 0; kk < 4; ++kk) {
                    #pragma unroll
                    for (int i = 0; i < 8; ++i) {
                        int k = p * 128 + kk * 32 + quad * 8 + i;
                        Wf[g][p][kk][i] = (bf16)Wg[g][k * 128 + n];
                    }
                }
    }

    float h[4] = {0.f, 0.f, 0.f, 0.f};   // lane-private hidden state

    float4 pf[4];
    float  pa = 0.f;
    auto issue_loads = [&](int c) {
        #pragma unroll
        for (int it = 0; it < 4; ++it) {
            int gidx = it * 512 + tid;
            int c4 = gidx & 31;
            int pair = gidx >> 5;
            int r = pair & 15;
            int s = pair >> 4;
            pf[it] = *(const float4*)(X + ((long)(b0 + r) * T_SZ + (c * ACHUNK + s)) * D_SZ + c4 * 4);
        }
        if (tid < ACHUNK * 16) {
            int r = tid & 15; int s = tid >> 4;
            pa = ATT[(long)(b0 + r) * T_SZ + c * ACHUNK + s];
        }
    };
    auto commit = [&](int buf) {
        #pragma unroll
        for (int it = 0; it < 4; ++it) {
            int gidx = it * 512 + tid;
            int c4 = gidx & 31;
            int pair = gidx >> 5;
            int r = pair & 15;
            int s = pair >> 4;
            bf16* dst = &Xs[buf][s][r][c4 * 4];
            float4 v = pf[it];
            dst[0] = (bf16)v.x; dst[1] = (bf16)v.y; dst[2] = (bf16)v.z; dst[3] = (bf16)v.w;
        }
        if (tid < ACHUNK * 16) { int r = tid & 15; int s = tid >> 4; As[buf][s][r] = pa; }
    };

    issue_loads(0);
    commit(0);
    __syncthreads();

    const int NCH = T_SZ / ACHUNK;   // 50
    for (int c = 0; c < NCH; ++c) {
        const int buf = c & 1;
        if (c + 1 < NCH) issue_loads(c + 1);

        #pragma unroll
        for (int s = 0; s < ACHUNK; ++s) {
            bf16x8 ax[4], ah[4];
            #pragma unroll
            for (int kk = 0; kk < 4; ++kk) {
                ax[kk] = *(const bf16x8*)&Xs[buf][s][l15][kk * 32 + quad * 8];
                ah[kk] = *(const bf16x8*)&Hb[l15][kk * 32 + quad * 8];
            }
            // ---- r gate (critical path) ----
            f32x4 pr = {};
            #pragma unroll
            for (int kk = 0; kk < 4; ++kk) pr = MFMA16(ax[kk], Wf[1][0][kk], pr);
            #pragma unroll
            for (int kk = 0; kk < 4; ++kk) pr = MFMA16(ah[kk], Wf[1][1][kk], pr);
            #pragma unroll
            for (int i = 0; i < 4; ++i) {
                int row = quad * 4 + i;
                float rr = fsig(pr[i]);
                RHb[row][n] = (bf16)(rr * h[i]);
            }
            // ---- u/c x-parts + u h-part: barrier-independent, hide the wait
            f32x4 pu = {}, pc = {};
            #pragma unroll
            for (int kk = 0; kk < 4; ++kk) {
                pu = MFMA16(ax[kk], Wf[0][0][kk], pu);
                pu = MFMA16(ah[kk], Wf[0][1][kk], pu);
                pc = MFMA16(ax[kk], Wf[2][0][kk], pc);
            }
            __syncthreads();
            // ---- c gate h-part ----
            bf16x8 ar[4];
            #pragma unroll
            for (int kk = 0; kk < 4; ++kk)
                ar[kk] = *(const bf16x8*)&RHb[l15][kk * 32 + quad * 8];
            #pragma unroll
            for (int kk = 0; kk < 4; ++kk) pc = MFMA16(ar[kk], Wf[2][1][kk], pc);
            #pragma unroll
            for (int i = 0; i < 4; ++i) {
                int row = quad * 4 + i;
                float a  = As[buf][s][row];
                float u  = fsig(pu[i]);
                float cg = ftanh_(pc[i]);
                float ut = u * a;
                float hn = (1.f - ut) * h[i] + ut * cg;
                h[i] = hn;
                Hb[row][n] = (bf16)hn;
            }
            __syncthreads();
        }
        if (c + 1 < NCH) commit(buf ^ 1);
        __syncthreads();
    }

    // write h_final from lane-private registers
    #pragma unroll
    for (int i = 0; i < 4; ++i)
        OUT[(long)(b0 + quad * 4 + i) * U_SZ + n] = h[i];
}

extern "C" void kernel_launch(void* const* d_in, const int* in_sizes, int n_in,
                              void* d_out, int out_size, void* d_ws, size_t ws_size,
                              hipStream_t stream) {
    const float* X   = (const float*)d_in[0];
    const float* Q   = (const float*)d_in[1];
    const int*   LEN = (const int*)d_in[2];
    const float* W1  = (const float*)d_in[3];
    const float* A1  = (const float*)d_in[4];
    const float* W2  = (const float*)d_in[5];
    const float* A2  = (const float*)d_in[6];
    const float* W3  = (const float*)d_in[7];
    const float* WU  = (const float*)d_in[8];
    const float* WR  = (const float*)d_in[9];
    const float* WC  = (const float*)d_in[10];
    float* OUT = (float*)d_out;

    // workspace layout
    float* ATT  = (float*)d_ws;                       // B*T fp32   (3.28 MB)
    float* BIAS = ATT + (size_t)B_SZ * T_SZ;          // B*64 fp32  (1.05 MB)
    bf16*  W1P  = (bf16*)(BIAS + (size_t)B_SZ * 64);  // 64*256 bf16
    bf16*  W2T  = W1P + 64 * 256;                     // 16*64 bf16

    prep_kernel<<<257, 256, 0, stream>>>(Q, W1, W2, BIAS, W1P, W2T);
    attn_kernel<<<B_SZ / ATTB, 256, 0, stream>>>(X, Q, LEN, A1, A2, W3, BIAS, W1P, W2T, ATT);
    augru_kernel<<<B_SZ / AROWS, 512, 0, stream>>>(X, ATT, WU, WR, WC, OUT);
}